// Round 7
// baseline (231.468 us; speedup 1.0000x reference)
//
#include <hip/hip_runtime.h>
#include <math.h>

// Problem constants
#define NTOK 8192
#define MDIM 4096
#define NEXP 64
#define CAPACITY 128.0f

// Output layout (all fp32): [indices 8192][capacity 1][locations 8192][gates 8192][num_experts 1]
#define OFF_IDX  0
#define OFF_CAP  8192
#define OFF_LOC  8193
#define OFF_GATE 16385
#define OFF_NE   24577

#define NSLICE 16                  // K-slices
#define KSL    (MDIM / NSLICE)     // 256 floats per slice
#define KC     32                  // K-chunk per MFMA step
#define NCH    (KSL / KC)          // 8 chunks (2 halves x 4)

// ws layout in 4-byte words: [cnt 256*64][rk 8192][part 16*8192*64]
#define WS_CNT_OFF  0
#define WS_RK_OFF   16384
#define WS_PART_OFF 24576

using bf16x8 = __attribute__((ext_vector_type(8))) short;
using f32x4  = __attribute__((ext_vector_type(4))) float;
typedef unsigned int u32;

// HW RNE f32x2 -> packed bf16x2 (gfx950 v_cvt_pk_bf16_f32; no builtin, T12).
// Bitwise-identical to the f2bf round-to-nearest-even bit trick.
static __device__ __forceinline__ u32 cvtpk(float a0, float a1) {
    u32 r;
    asm("v_cvt_pk_bf16_f32 %0, %1, %2" : "=v"(r) : "v"(a0), "v"(a1));
    return r;
}

// 3-term split of an f32 pair into 3 packed-bf16 words (hi/mid/lo planes).
static __device__ __forceinline__ void split2(
    float a0, float a1, u32& p1, u32& p2, u32& p3)
{
    p1 = cvtpk(a0, a1);
    float t0 = a0 - __uint_as_float(p1 << 16);
    float t1 = a1 - __uint_as_float(p1 & 0xffff0000u);
    p2 = cvtpk(t0, t1);
    float u0 = t0 - __uint_as_float(p2 << 16);
    float u1 = t1 - __uint_as_float(p2 & 0xffff0000u);
    p3 = cvtpk(u0, u1);
}

// ---------------------------------------------------------------------------
// Gate GEMM v6: half-slice W staging -> 80 KB LDS -> 2 blocks/CU.
//  - Round-6 post-mortem: 128 KB LDS (96K W + 32K x) capped at 1 block/CU
//    = 2 waves/SIMD; all pipes <17%, ~85% stall. Fix: stage W in TWO 48 KB
//    halves (4 chunks each) re-split mid-block -> LDS 48+32=80 KB, 2
//    blocks/CU, 16 waves/CU. Plus hardware cvt_pk (RNE, bit-identical to
//    f2bf) cuts the fp32->3xbf16 split VALU ~2.5x in loop AND prologue.
//  - Everything else is round-6 verified: wave-private x DMA (only vmcnt
//    traffic in the loop), swizzled W/x LDS layouts, 6-product MFMA order.
// ---------------------------------------------------------------------------
__global__ __launch_bounds__(512, 4) void gate_mfma(
    const float* __restrict__ x,
    const float* __restrict__ W,
    float* __restrict__ part)
{
    // [ (c&3)*3+t ][expert][32 bf16], 16B slots XOR-swizzled by ((e>>1)&3)
    __shared__ __align__(16) unsigned short wl[12][64][32];   // 48 KB
    // per-wave x chunk: [wave][token row 0..31][f4 slot 0..7], row-swizzled
    __shared__ __align__(16) float4 xs[8][32][8];             // 32 KB

    const int tid   = threadIdx.x;
    const int lane  = tid & 63;
    const int wv    = tid >> 6;                // 0..7
    const int m     = lane & 15;
    const int g     = lane >> 4;               // 0..3
    const int tok0  = blockIdx.x * 256 + wv * 32;
    const int slice = blockIdx.y;
    const int k0    = slice * KSL;

    const float4* __restrict__ x4 = (const float4*)x;

    // ---- wave-private async x stage of chunk c into xs[wv] -------------
    auto stage = [&](int c) {
        #pragma unroll
        for (int j = 0; j < 4; ++j) {
            const int row  = j * 8 + (lane >> 3);
            const int srcs = (lane & 7) ^ (row & 7);
            const float4* gsrc = x4 + (size_t)(tok0 + row) * (MDIM / 4)
                                 + (k0 >> 2) + c * 8 + srcs;
            void* ldst = (void*)&xs[wv][j * 8][0];   // +lane*16 by HW
            __builtin_amdgcn_global_load_lds(
                (const __attribute__((address_space(1))) void*)gsrc,
                (__attribute__((address_space(3))) void*)ldst, 16, 0, 0);
        }
    };

    // ---- W half-slice split: 32 KB fp32 -> 3 bf16 planes (24 KB) -------
    // half h covers chunks 4h..4h+3; 2048 float4s, 512 thr x 4.
    auto splitW = [&](int h) {
        #pragma unroll
        for (int r = 0; r < 4; ++r) {
            const int j4  = r * 512 + tid;      // 0..2047
            const int e   = j4 >> 5;            // expert
            const int kk4 = j4 & 31;            // float4 within 128-col half
            float4 v = *(const float4*)(W + (size_t)e * MDIM + k0 + h * 128 + kk4 * 4);
            const int c4    = kk4 >> 3;         // chunk-in-half 0..3
            const int slog  = (kk4 >> 1) & 3;
            const int half16 = kk4 & 1;
            const int phys  = slog ^ ((e >> 1) & 3);
            u32 w1a, w2a, w3a, w1b, w2b, w3b;
            split2(v.x, v.y, w1a, w2a, w3a);
            split2(v.z, v.w, w1b, w2b, w3b);
            *(uint2*)&wl[c4 * 3 + 0][e][phys * 8 + half16 * 4] = make_uint2(w1a, w1b);
            *(uint2*)&wl[c4 * 3 + 1][e][phys * 8 + half16 * 4] = make_uint2(w2a, w2b);
            *(uint2*)&wl[c4 * 3 + 2][e][phys * 8 + half16 * 4] = make_uint2(w3a, w3b);
        }
    };

    // 8 fp32 -> 3 bf16x8 planes via cvt_pk (bit-identical to f2bf RNE)
    auto cvt = [&](float4 lo, float4 hi, bf16x8& r0, bf16x8& r1, bf16x8& r2) {
        union { u32 u[4]; bf16x8 v; } P1, P2, P3;
        split2(lo.x, lo.y, P1.u[0], P2.u[0], P3.u[0]);
        split2(lo.z, lo.w, P1.u[1], P2.u[1], P3.u[1]);
        split2(hi.x, hi.y, P1.u[2], P2.u[2], P3.u[2]);
        split2(hi.z, hi.w, P1.u[3], P2.u[3], P3.u[3]);
        r0 = P1.v; r1 = P2.v; r2 = P3.v;
    };

    f32x4 acc[2][4];
    #pragma unroll
    for (int gr = 0; gr < 2; ++gr)
        #pragma unroll
        for (int nt = 0; nt < 4; ++nt) acc[gr][nt] = (f32x4){0.f, 0.f, 0.f, 0.f};

    stage(0);   // overlaps the first W split; drained at the barrier

    for (int h = 0; h < 2; ++h) {
        if (h) __syncthreads();    // all waves done reading wl half-0
        splitW(h);
        __syncthreads();           // W half ready (x DMA drained too)

        #pragma unroll
        for (int c4 = 0; c4 < 4; ++c4) {
            const int c = h * 4 + c4;

            // W frags from LDS (lgkm domain; swizzled, 2-way = free)
            bf16x8 w[3][4];
            #pragma unroll
            for (int t = 0; t < 3; ++t)
                #pragma unroll
                for (int nt = 0; nt < 4; ++nt) {
                    const int e    = nt * 16 + m;
                    const int phys = g ^ ((e >> 1) & 3);
                    w[t][nt] = *(const bf16x8*)&wl[c4 * 3 + t][e][phys * 8];
                }

            // x frags (vmcnt wait covers only this wave's 4 DMAs)
            bf16x8 a[2][3];
            #pragma unroll
            for (int gr = 0; gr < 2; ++gr) {
                const int row = gr * 16 + m;
                float4 lo = xs[wv][row][(2 * g    ) ^ (m & 7)];
                float4 hi = xs[wv][row][(2 * g + 1) ^ (m & 7)];
                cvt(lo, hi, a[gr][0], a[gr][1], a[gr][2]);
            }

            // x regs extracted -> safe to overwrite the wave's buffer
            __builtin_amdgcn_sched_barrier(0);
            if (c + 1 < NCH) stage(c + 1);   // HBM latency hides under MFMAs

            // 6 split-products (verified order), 2 groups x 4 nt chains
            #pragma unroll
            for (int gr = 0; gr < 2; ++gr)
                #pragma unroll
                for (int nt = 0; nt < 4; ++nt)
                    acc[gr][nt] = __builtin_amdgcn_mfma_f32_16x16x32_bf16(a[gr][2], w[0][nt], acc[gr][nt], 0, 0, 0);
            #pragma unroll
            for (int gr = 0; gr < 2; ++gr)
                #pragma unroll
                for (int nt = 0; nt < 4; ++nt)
                    acc[gr][nt] = __builtin_amdgcn_mfma_f32_16x16x32_bf16(a[gr][0], w[2][nt], acc[gr][nt], 0, 0, 0);
            #pragma unroll
            for (int gr = 0; gr < 2; ++gr)
                #pragma unroll
                for (int nt = 0; nt < 4; ++nt)
                    acc[gr][nt] = __builtin_amdgcn_mfma_f32_16x16x32_bf16(a[gr][1], w[1][nt], acc[gr][nt], 0, 0, 0);
            #pragma unroll
            for (int gr = 0; gr < 2; ++gr)
                #pragma unroll
                for (int nt = 0; nt < 4; ++nt)
                    acc[gr][nt] = __builtin_amdgcn_mfma_f32_16x16x32_bf16(a[gr][1], w[0][nt], acc[gr][nt], 0, 0, 0);
            #pragma unroll
            for (int gr = 0; gr < 2; ++gr)
                #pragma unroll
                for (int nt = 0; nt < 4; ++nt)
                    acc[gr][nt] = __builtin_amdgcn_mfma_f32_16x16x32_bf16(a[gr][0], w[1][nt], acc[gr][nt], 0, 0, 0);
            #pragma unroll
            for (int gr = 0; gr < 2; ++gr)
                #pragma unroll
                for (int nt = 0; nt < 4; ++nt)
                    acc[gr][nt] = __builtin_amdgcn_mfma_f32_16x16x32_bf16(a[gr][0], w[0][nt], acc[gr][nt], 0, 0, 0);
        }
    }

    // C/D layout (m89-verified): col = lane&15, row = (lane>>4)*4 + reg.
    #pragma unroll
    for (int gr = 0; gr < 2; ++gr)
        #pragma unroll
        for (int nt = 0; nt < 4; ++nt)
            #pragma unroll
            for (int r = 0; r < 4; ++r) {
                const int tokr = tok0 + gr * 16 + g * 4 + r;
                part[((size_t)slice * NTOK + tokr) * 64 + nt * 16 + m] = acc[gr][nt][r];
            }
}

// ---------------------------------------------------------------------------
// Fused reduce + argmax/softmax + per-32-token-chunk histogram/rank.
// 256 blocks x 256 thr; 32 tokens/block, 8 lanes per token. (unchanged)
// ---------------------------------------------------------------------------
template<int S>
__global__ __launch_bounds__(256) void reduce_count(
    const float* __restrict__ part,
    float* __restrict__ out,
    int* __restrict__ cnt,
    int* __restrict__ rk)
{
    __shared__ int eidx[32];

    const int tid  = threadIdx.x;
    const int tok0 = blockIdx.x * 32;
    const int trel = tid >> 3;          // 0..31
    const int tok  = tok0 + trel;
    const int q    = tid & 7;           // expert octet

    const float4* __restrict__ p4 = (const float4*)part;

    float4 a[2];
    #pragma unroll
    for (int r = 0; r < 2; ++r) a[r] = make_float4(0.f, 0.f, 0.f, 0.f);
    for (int s = 0; s < S; ++s) {
        #pragma unroll
        for (int r = 0; r < 2; ++r) {
            float4 v = p4[((size_t)s * NTOK + tok) * 16 + q * 2 + r];
            a[r].x += v.x; a[r].y += v.y; a[r].z += v.z; a[r].w += v.w;
        }
    }

    float vals[8] = {a[0].x, a[0].y, a[0].z, a[0].w,
                     a[1].x, a[1].y, a[1].z, a[1].w};

    float bm = vals[0];
    int   be = q * 8;
    #pragma unroll
    for (int j = 1; j < 8; ++j)
        if (vals[j] > bm) { bm = vals[j]; be = q * 8 + j; }
    #pragma unroll
    for (int off = 1; off <= 4; off <<= 1) {
        float om = __shfl_xor(bm, off, 64);
        int   oe = __shfl_xor(be, off, 64);
        if (om > bm || (om == bm && oe < be)) { bm = om; be = oe; }
    }

    float es = 0.f;
    #pragma unroll
    for (int j = 0; j < 8; ++j) es += expf(vals[j] - bm);
    #pragma unroll
    for (int off = 1; off <= 4; off <<= 1)
        es += __shfl_xor(es, off, 64);

    if (q == 0) {
        out[OFF_IDX  + tok] = (float)be;
        out[OFF_GATE + tok] = 1.0f / es;
        eidx[trel] = be;
    }
    __syncthreads();

    if (tid < 64) {  // wave 0: histogram of the 32 tokens over 64 experts
        const int e = (tid < 32) ? eidx[tid] : -1;
        const unsigned long long lt =
            (tid == 0) ? 0ull : ((~0ull) >> (64 - tid));
        unsigned long long mymask = 0;
        int myrk = 0;
        for (int ee = 0; ee < 64; ++ee) {
            unsigned long long mb = __ballot(e == ee);
            if (tid == ee) mymask = mb;          // tid = expert id
            if (e == ee)   myrk   = (int)__popcll(mb & lt);
        }
        cnt[blockIdx.x * 64 + tid] = (int)__popcll(mymask);
        if (tid < 32) rk[tok0 + tid] = myrk;
    }
    if (tid == 0 && blockIdx.x == 0) {
        out[OFF_CAP] = CAPACITY;
        out[OFF_NE]  = (float)NEXP;
    }
}

// ---------------------------------------------------------------------------
// Fused scan + emit, ONE block x 512 thr. (unchanged)
// ---------------------------------------------------------------------------
__global__ __launch_bounds__(512) void scan_emit(
    const float* __restrict__ idxf,
    const int* __restrict__ cnt,
    const int* __restrict__ rk,
    float* __restrict__ out)
{
    __shared__ int sc[256][64];   // 64 KB, [chunk][e] -> becomes excl. base
    __shared__ int ps[64][8];     // per-(expert, segment) totals

    const int tid = threadIdx.x;
    const int e   = tid >> 3;     // 0..63
    const int q   = tid & 7;      // segment 0..7 (32 chunks each)

    #pragma unroll
    for (int r = 0; r < 32; ++r) sc[0][r * 512 + tid] = cnt[r * 512 + tid];
    __syncthreads();

    {   // segment totals
        int sum = 0;
        #pragma unroll
        for (int j = 0; j < 32; ++j) sum += sc[q * 32 + j][e];
        ps[e][q] = sum;
    }
    __syncthreads();

    {   // exclusive base across segments, then in-place chunk scan
        int base = 0;
        for (int qq = 0; qq < 8; ++qq) { if (qq < q) base += ps[e][qq]; }
        #pragma unroll
        for (int j = 0; j < 32; ++j) {
            int ch = q * 32 + j;
            int v  = sc[ch][e];
            sc[ch][e] = base;
            base += v;
        }
    }
    __syncthreads();

    #pragma unroll
    for (int r = 0; r < 16; ++r) {
        const int s  = r * 512 + tid;
        const int ee = (int)idxf[s];
        out[OFF_LOC + s] = (float)(sc[s >> 5][ee] + rk[s]);
    }
}

extern "C" void kernel_launch(void* const* d_in, const int* in_sizes, int n_in,
                              void* d_out, int out_size, void* d_ws, size_t ws_size,
                              hipStream_t stream)
{
    const float* x = (const float*)d_in[0];   // [8192, 4096] fp32
    const float* W = (const float*)d_in[1];   // [64, 4096] fp32
    float* out = (float*)d_out;               // 24578 fp32

    int*   cnt  = (int*)d_ws + WS_CNT_OFF;
    int*   rk   = (int*)d_ws + WS_RK_OFF;
    float* part = (float*)d_ws + WS_PART_OFF;
    // ws need: (24576 + 16*8192*64) * 4B ~ 33.7 MB (proven to fit, round 6)

    gate_mfma<<<dim3(32, NSLICE), 512, 0, stream>>>(x, W, part);
    reduce_count<NSLICE><<<256, 256, 0, stream>>>(part, out, cnt, rk);
    scan_emit<<<1, 512, 0, stream>>>(out + OFF_IDX, cnt, rk, out);
}